// Round 1
// 1267.034 us; speedup vs baseline: 1.0204x; 1.0204x over previous
//
#include <hip/hip_runtime.h>
#include <cstdint>

// Instant-NGP hash-grid encoder, D=3, L=16, C=2, H=16, PS=2, T=2^19.
// Round-3: attack gather latency-boundedness + transpose width.
//   Evidence: gather VGPR_Count=56 proves the compiler re-interleaved the
//   "issue all 32 gathers" block down to ~8 outstanding loads/wave
//   (0.47 gathers/cy/CU == 13 waves x 8 loads / ~220cy L2 latency).
//   Fix: sched_barrier(0) between the load cluster and the combine loop
//   pins all 32 loads above all consumers (VGPR ~150, 3 waves/SIMD,
//   4x outstanding lines per CU). Weights are recomputed AFTER the
//   barrier from cached fracs so VALU work overlaps load latency.
//   Transpose: ws (268MB) spills L3 -> ~900cy HBM reads; old kernel was
//   8B/lane at 50% occupancy => 1.5 TB/s. New: float4 both global sides,
//   128-pt tile (18KB LDS => 8 blocks/CU), XOR cell-swizzle
//   (c2' = l ^ ((row>>1)&15), stride 36 floats) => conflict-free LDS.
// NUMERICS: pos = x01*scale + 0.5 must be two separately-rounded f32 ops
// (numpy semantics); __fmul_rn/__fadd_rn block FMA contraction there.

static constexpr uint32_t PRIME1 = 2654435761u;
static constexpr uint32_t PRIME2 = 805459861u;
static constexpr uint32_t HASH_MASK = (1u << 19) - 1u;

__constant__ uint32_t c_offs[16] = {
    0u, 4920u, 40864u, 315496u, 839784u, 1364072u, 1888360u, 2412648u,
    2936936u, 3461224u, 3985512u, 4509800u, 5034088u, 5558376u,
    6082664u, 6606952u};

__global__ __launch_bounds__(256) void gather_kernel(
    const float* __restrict__ inputs,      // [B,3]
    const float* __restrict__ embeddings,  // [4920,2] (level-0 rows)
    const float* __restrict__ table,       // [TOTAL-4920,2]
    float2* __restrict__ dst,              // staged: ws[l*B + b] ; direct: out_f2[b*16 + l]
    int B, int chunks, int directOut)
{
    // --- block -> (level, chunk) with XCD pinning ---
    const int j   = blockIdx.x;
    const int xcd = j & 7;
    const int s   = j >> 3;
    const int lvl = 2 * xcd + (s >= chunks ? 1 : 0);
    const int chunk = (s >= chunks) ? (s - chunks) : s;
    const int base  = chunk * 1024;           // 4 points/thread * 256 threads
    const int tid   = threadIdx.x;

    // --- stage this chunk's inputs through LDS (coalesced) ---
    __shared__ float sIn[3072];
    {
        const float* gp = inputs + (size_t)base * 3;
        const int lim = B * 3 - base * 3;
#pragma unroll
        for (int k = 0; k < 12; ++k) {
            const int i = tid + k * 256;
            sIn[i] = (i < lim) ? gp[i] : 0.0f;   // zero-fill: safe idx on tail
        }
    }
    __syncthreads();

    // --- level-dependent constants (block-uniform) ---
    const float scale = (float)((16u << lvl) - 1u);   // exactly representable
    const uint32_t off = c_offs[lvl];
    const float2* __restrict__ tb = (lvl == 0)
        ? (const float2*)embeddings
        : ((const float2*)table) + (off - 4920u);
    const bool dense = (lvl < 3);
    const uint32_t dstr  = (16u << lvl) + 1u;   // dense row stride
    const uint32_t dstr2 = dstr * dstr;

    uint32_t idx[4][8];
    float fx[4], fy[4], fz[4];

#pragma unroll
    for (int p = 0; p < 4; ++p) {
        const int li = p * 256 + tid;           // local point index
        // bound=1: x01=(x+1)/2 (add rounds once, *0.5 exact)
        const float x01 = __fadd_rn(sIn[li * 3 + 0], 1.0f) * 0.5f;
        const float y01 = __fadd_rn(sIn[li * 3 + 1], 1.0f) * 0.5f;
        const float z01 = __fadd_rn(sIn[li * 3 + 2], 1.0f) * 0.5f;

        // pos = x01*scale + 0.5 : two separately-rounded ops (NO fma)
        const float px = __fadd_rn(__fmul_rn(x01, scale), 0.5f);
        const float py = __fadd_rn(__fmul_rn(y01, scale), 0.5f);
        const float pz = __fadd_rn(__fmul_rn(z01, scale), 0.5f);

        const float fxf = floorf(px), fyf = floorf(py), fzf = floorf(pz);
        fx[p] = px - fxf;  fy[p] = py - fyf;  fz[p] = pz - fzf;   // exact
        const uint32_t ix = (uint32_t)fxf, iy = (uint32_t)fyf, iz = (uint32_t)fzf;

        if (dense) {
            const uint32_t oy0 = iy * dstr,  oy1 = oy0 + dstr;
            const uint32_t oz0 = iz * dstr2, oz1 = oz0 + dstr2;
            idx[p][0] = ix + oy0 + oz0;  idx[p][1] = idx[p][0] + 1u;
            idx[p][2] = ix + oy1 + oz0;  idx[p][3] = idx[p][2] + 1u;
            idx[p][4] = ix + oy0 + oz1;  idx[p][5] = idx[p][4] + 1u;
            idx[p][6] = ix + oy1 + oz1;  idx[p][7] = idx[p][6] + 1u;
        } else {
            const uint32_t hy0 = iy * PRIME1, hy1 = hy0 + PRIME1;  // u32 wrap
            const uint32_t hz0 = iz * PRIME2, hz1 = hz0 + PRIME2;
            const uint32_t a00 = hy0 ^ hz0, a10 = hy1 ^ hz0;
            const uint32_t a01 = hy0 ^ hz1, a11 = hy1 ^ hz1;
            idx[p][0] = (ix ^ a00) & HASH_MASK;  idx[p][1] = ((ix + 1u) ^ a00) & HASH_MASK;
            idx[p][2] = (ix ^ a10) & HASH_MASK;  idx[p][3] = ((ix + 1u) ^ a10) & HASH_MASK;
            idx[p][4] = (ix ^ a01) & HASH_MASK;  idx[p][5] = ((ix + 1u) ^ a01) & HASH_MASK;
            idx[p][6] = (ix ^ a11) & HASH_MASK;  idx[p][7] = ((ix + 1u) ^ a11) & HASH_MASK;
        }
    }

    // --- issue ALL 32 gathers; sched_barrier(0) forbids the scheduler from
    //     sinking any load below it / hoisting any consumer above it, so all
    //     32 stay in flight per wave (deliberate pinning). ---
    float2 e[4][8];
#pragma unroll
    for (int p = 0; p < 4; ++p)
#pragma unroll
        for (int c = 0; c < 8; ++c)
            e[p][c] = tb[idx[p][c]];
    __builtin_amdgcn_sched_barrier(0);

    // --- weights (VALU, independent of loads -> overlaps load latency),
    //     then combine + write ---
#pragma unroll
    for (int p = 0; p < 4; ++p) {
        const int b = base + p * 256 + tid;
        if (b >= B) continue;
        const float tx = fx[p], ty = fy[p], tz = fz[p];
        const float wx0 = 1.0f - tx, wy0 = 1.0f - ty, wz0 = 1.0f - tz;
        // ((x)*(y))*(z) product order matches jnp.prod
        const float wxy00 = __fmul_rn(wx0, wy0), wxy10 = __fmul_rn(tx, wy0);
        const float wxy01 = __fmul_rn(wx0, ty),  wxy11 = __fmul_rn(tx, ty);
        float w[8];
        w[0] = __fmul_rn(wxy00, wz0); w[1] = __fmul_rn(wxy10, wz0);
        w[2] = __fmul_rn(wxy01, wz0); w[3] = __fmul_rn(wxy11, wz0);
        w[4] = __fmul_rn(wxy00, tz);  w[5] = __fmul_rn(wxy10, tz);
        w[6] = __fmul_rn(wxy01, tz);  w[7] = __fmul_rn(wxy11, tz);

        float r0 = __fmul_rn(w[0], e[p][0].x);
        float r1 = __fmul_rn(w[0], e[p][0].y);
#pragma unroll
        for (int c = 1; c < 8; ++c) {
            r0 = fmaf(w[c], e[p][c].x, r0);
            r1 = fmaf(w[c], e[p][c].y, r1);
        }
        if (directOut) {
            dst[(size_t)b * 16 + lvl] = make_float2(r0, r1);
        } else {
            dst[(size_t)lvl * B + b] = make_float2(r0, r1);
        }
    }
}

// ws[16][B] float2 (level-major)  ->  out[B][32] float (point-major)
// 128-point tile, float4 on both global sides, XOR-swizzled LDS:
//   logical float2-cell c2=l of row r stored at c2' = l ^ ((r>>1)&15),
//   row stride 36 floats (144B, 16B-aligned). Read side fetches the
//   aligned float4 containing cells {2j,2j+1}; halves are swapped when
//   ((p>>1)&1) because odd XOR keys flip bit0 of the cell index.
__global__ __launch_bounds__(256) void transpose_kernel(
    const float2* __restrict__ ws, float* __restrict__ out, int B)
{
    __shared__ float sT[128 * 36];   // 18432 B -> 8 blocks/CU
    const int tid = threadIdx.x;
    const int b0  = blockIdx.x * 128;
    const bool full = (b0 + 128 <= B);

#pragma unroll
    for (int k = 0; k < 4; ++k) {
        const int idx = k * 256 + tid;   // 0..1023
        const int l   = idx >> 6;        // level 0..15 (wave-uniform)
        const int q   = idx & 63;        // point-pair 0..63
        const int b   = b0 + 2 * q;
        float4 v = make_float4(0.f, 0.f, 0.f, 0.f);
        if (full) {
            v = *(const float4*)(&ws[(size_t)l * B + b]);   // 2 points, 16B
        } else {
            if (b < B)     { float2 t = ws[(size_t)l * B + b];     v.x = t.x; v.y = t.y; }
            if (b + 1 < B) { float2 t = ws[(size_t)l * B + b + 1]; v.z = t.x; v.w = t.y; }
        }
        const int c2 = l ^ (q & 15);     // swizzled float2-cell (both rows share q)
        *(float2*)&sT[(2 * q)     * 36 + 2 * c2] = make_float2(v.x, v.y);
        *(float2*)&sT[(2 * q + 1) * 36 + 2 * c2] = make_float2(v.z, v.w);
    }
    __syncthreads();

    float4* orow = (float4*)(out + (size_t)b0 * 32);
    const int lim4 = (B - b0) * 8;       // valid float4 chunks in this tile
#pragma unroll
    for (int k = 0; k < 4; ++k) {
        const int f = k * 256 + tid;     // 0..1023
        if (f >= lim4) continue;
        const int p = f >> 3;            // point 0..127
        const int jj = f & 7;            // output float4 chunk 0..7
        const int q = p >> 1;
        const int y = (2 * jj) ^ (q & 15);
        const float4 v = *(const float4*)&sT[p * 36 + 2 * (y & ~1)];
        orow[f] = (q & 1) ? make_float4(v.z, v.w, v.x, v.y) : v;
    }
}

extern "C" void kernel_launch(void* const* d_in, const int* in_sizes, int n_in,
                              void* d_out, int out_size, void* d_ws, size_t ws_size,
                              hipStream_t stream) {
    const float* inputs     = (const float*)d_in[0];
    const float* embeddings = (const float*)d_in[1];
    const float* table      = (const float*)d_in[2];
    float* out              = (float*)d_out;

    const int B = in_sizes[0] / 3;
    const int chunks = (B + 1023) / 1024;
    const size_t need = (size_t)16 * (size_t)B * sizeof(float2);
    const bool staged = ws_size >= need;

    gather_kernel<<<16 * chunks, 256, 0, stream>>>(
        inputs, embeddings, table,
        staged ? (float2*)d_ws : (float2*)d_out,
        B, chunks, staged ? 0 : 1);

    if (staged) {
        transpose_kernel<<<(B + 127) / 128, 256, 0, stream>>>(
            (const float2*)d_ws, out, B);
    }
}